// Round 5
// baseline (479.054 us; speedup 1.0000x reference)
//
#include <hip/hip_runtime.h>
#include <cmath>

// Problem constants
#define BB   8192
#define ZD   16
#define DH   1024
#define DX   3072
#define M2   (2*BB)

static constexpr float LOG2PI_F = 1.8378770664093453f;
static constexpr float CLAMP_F  = 1000000.0f;

using half8  = __attribute__((ext_vector_type(8))) _Float16;
using half4v = __attribute__((ext_vector_type(4))) _Float16;
using f32x4  = __attribute__((ext_vector_type(4))) float;

__device__ __forceinline__ float clampv(float x){
    return fminf(fmaxf(x, -CLAMP_F), CLAMP_F);
}

__device__ __forceinline__ void gload_lds16(const void* g, void* l){
    __builtin_amdgcn_global_load_lds(
        (const __attribute__((address_space(1))) unsigned int*)g,
        (__attribute__((address_space(3))) unsigned int*)l,
        16, 0, 0);
}

#define BAR()  asm volatile("s_barrier" ::: "memory")
#define LGKM0() do{ asm volatile("s_waitcnt lgkmcnt(0)" ::: "memory"); \
                    __builtin_amdgcn_sched_barrier(0); }while(0)

// ---------------------------------------------------------------------------
__global__ void init_acc(double* acc){
    if (threadIdx.x == 0) acc[0] = 0.0;
}

__global__ void finalize_kernel(const double* __restrict__ acc, float* __restrict__ out){
    if (threadIdx.x == 0){
        const double LOG17 = 2.8332133440562162;
        const double log_p_I = -LOG17 * (double)BB;
        out[(size_t)2 * BB * DX] = (float)(acc[0] + log_p_I);
    }
}

// ---------------------------------------------------------------------------
// Flow network (unchanged — correctness-proven, ~15 µs)
// ---------------------------------------------------------------------------
__global__ __launch_bounds__(256)
void flow_kernel(const float* __restrict__ e1, const float* __restrict__ e2,
                 const float* __restrict__ interv,
                 const float* __restrict__ W1, const float* __restrict__ b1,
                 const float* __restrict__ W2, const float* __restrict__ b2,
                 const float* __restrict__ W3, const float* __restrict__ b3,
                 double* __restrict__ acc)
{
    const int i = blockIdx.y;
    const int b = blockIdx.x * 256 + threadIdx.x;

    float ex[16];
    #pragma unroll
    for (int d = 0; d < 16; d += 4){
        const float4 v = *reinterpret_cast<const float4*>(&e1[(size_t)b*16 + d]);
        ex[d] = v.x; ex[d+1] = v.y; ex[d+2] = v.z; ex[d+3] = v.w;
    }

    float lp1 = 0.f;
    if (i == 0){
        #pragma unroll
        for (int d = 0; d < 16; ++d){
            const float t = -0.5f*ex[d]*ex[d] - 0.5f*LOG2PI_F;
            lp1 += clampv(t);
        }
    }

    #pragma unroll
    for (int d = 0; d < 16; ++d)
        if (d == i) ex[d] = 0.f;

    float h1[64];
    #pragma unroll
    for (int h = 0; h < 64; h += 4){
        const float4 bv = *reinterpret_cast<const float4*>(&b1[i*64 + h]);
        h1[h] = bv.x; h1[h+1] = bv.y; h1[h+2] = bv.z; h1[h+3] = bv.w;
    }
    for (int d = 0; d < 16; ++d){
        const float c = ex[d];
        const float* w = &W1[((size_t)i*16 + d)*64];
        #pragma unroll
        for (int h = 0; h < 64; h += 4){
            const float4 wv = *reinterpret_cast<const float4*>(&w[h]);
            h1[h]   = fmaf(c, wv.x, h1[h]);
            h1[h+1] = fmaf(c, wv.y, h1[h+1]);
            h1[h+2] = fmaf(c, wv.z, h1[h+2]);
            h1[h+3] = fmaf(c, wv.w, h1[h+3]);
        }
    }
    #pragma unroll
    for (int h = 0; h < 64; ++h) h1[h] = fmaxf(h1[h], 0.f);

    float hk[64];
    #pragma unroll
    for (int k = 0; k < 64; k += 4){
        const float4 bv = *reinterpret_cast<const float4*>(&b2[i*64 + k]);
        hk[k] = bv.x; hk[k+1] = bv.y; hk[k+2] = bv.z; hk[k+3] = bv.w;
    }
    for (int h = 0; h < 64; ++h){
        const float hv = h1[h];
        const float* w = &W2[((size_t)i*64 + h)*64];
        #pragma unroll
        for (int k = 0; k < 64; k += 4){
            const float4 wv = *reinterpret_cast<const float4*>(&w[k]);
            hk[k]   = fmaf(hv, wv.x, hk[k]);
            hk[k+1] = fmaf(hv, wv.y, hk[k+1]);
            hk[k+2] = fmaf(hv, wv.z, hk[k+2]);
            hk[k+3] = fmaf(hv, wv.w, hk[k+3]);
        }
    }
    #pragma unroll
    for (int k = 0; k < 64; ++k) hk[k] = fmaxf(hk[k], 0.f);

    float p0 = b3[i*2 + 0];
    float p1 = b3[i*2 + 1];
    for (int k = 0; k < 64; ++k){
        const float2 wv = *reinterpret_cast<const float2*>(&W3[((size_t)i*64 + k)*2]);
        p0 = fmaf(hk[k], wv.x, p0);
        p1 = fmaf(hk[k], wv.y, p1);
    }

    const float shift = p0;
    const float sp    = (p1 > 20.f) ? p1 : log1pf(expf(p1));
    const float scale = sp + 0.2f;
    float z = (e2[(size_t)b*16 + i] - shift) / scale;
    z = clampv(z);
    const float mask = interv[(size_t)b*17 + i + 1];
    const float term = (-0.5f*z*z - 0.5f*LOG2PI_F - logf(scale)) * mask;

    double v = (double)term + (double)lp1;

    #pragma unroll
    for (int off = 32; off; off >>= 1) v += __shfl_down(v, off, 64);
    __shared__ double sred[4];
    if ((threadIdx.x & 63) == 0) sred[threadIdx.x >> 6] = v;
    __syncthreads();
    if (threadIdx.x == 0){
        const double s = sred[0] + sred[1] + sred[2] + sred[3];
        atomicAdd(acc, s);
    }
}

// ---------------------------------------------------------------------------
// Transpose + fp32->fp16 convert: Wt[n][k] = (half)W[k][n]
// ---------------------------------------------------------------------------
__global__ __launch_bounds__(256)
void convT_kernel(const float* __restrict__ W, _Float16* __restrict__ Wt,
                  int K, int N)
{
    __shared__ float s[32][33];
    const int n0 = blockIdx.x * 32;
    const int k0 = blockIdx.y * 32;
    const int t  = threadIdx.x;
    const int r  = t >> 3;
    const int c4 = (t & 7) * 4;

    const float4 v = *reinterpret_cast<const float4*>(&W[(size_t)(k0 + r)*N + n0 + c4]);
    s[r][c4+0] = v.x; s[r][c4+1] = v.y; s[r][c4+2] = v.z; s[r][c4+3] = v.w;
    __syncthreads();

    half4v o;
    o[0] = (_Float16)s[c4+0][r];
    o[1] = (_Float16)s[c4+1][r];
    o[2] = (_Float16)s[c4+2][r];
    o[3] = (_Float16)s[c4+3][r];
    *reinterpret_cast<half4v*>(&Wt[(size_t)(n0 + r)*K + k0 + c4]) = o;
}

// ---------------------------------------------------------------------------
// Decoder layer 1, tiled: 32 rows x 1024 cols per block, Wd1 in registers.
// L2 traffic: 512 blocks x 64 KB = 32 MB (was 1 GB with 1-row blocks).
// ---------------------------------------------------------------------------
__global__ __launch_bounds__(256)
void dec1_tiled(const float* __restrict__ e1, const float* __restrict__ e2,
                const float* __restrict__ Wd1, const float* __restrict__ bd1,
                _Float16* __restrict__ hh1)
{
    __shared__ float es[32][16];
    const int blk  = blockIdx.x;            // 0..511
    const int tid  = threadIdx.x;
    const int row0 = blk * 32;              // global row (0..16383)
    const float* e = (blk < 256) ? &e1[(size_t)row0*16]
                                 : &e2[(size_t)(row0 - BB)*16];

    // stage 32x16 e-rows: 2 floats/thread
    {
        const int idx = tid * 2;            // 0..510
        const float2 v = *reinterpret_cast<const float2*>(&e[idx]);
        es[idx >> 4][idx & 15]       = v.x;
        es[idx >> 4][(idx & 15) + 1] = v.y;
    }

    // Wd1 column-slice in registers: 16 x float4
    const int c0 = tid * 4;
    float4 w[16];
    #pragma unroll
    for (int k = 0; k < 16; ++k)
        w[k] = *reinterpret_cast<const float4*>(&Wd1[(size_t)k*DH + c0]);
    const float4 bv = *reinterpret_cast<const float4*>(&bd1[c0]);
    __syncthreads();

    for (int r = 0; r < 32; ++r){
        float4 a = bv;
        #pragma unroll
        for (int k = 0; k < 16; ++k){
            const float ev = es[r][k];
            a.x = fmaf(ev, w[k].x, a.x);
            a.y = fmaf(ev, w[k].y, a.y);
            a.z = fmaf(ev, w[k].z, a.z);
            a.w = fmaf(ev, w[k].w, a.w);
        }
        half4v o;
        o[0] = (_Float16)fmaxf(a.x, 0.f);
        o[1] = (_Float16)fmaxf(a.y, 0.f);
        o[2] = (_Float16)fmaxf(a.z, 0.f);
        o[3] = (_Float16)fmaxf(a.w, 0.f);
        *reinterpret_cast<half4v*>(&hh1[(size_t)(row0 + r)*DH + c0]) = o;
    }
}

// ---------------------------------------------------------------------------
// fp16 MFMA GEMM, 256x256 tile, BK=64, 8 waves (2M x 4N), 512 threads.
// 8-phase schedule (T3+T4+T5), 2 K-tiles/iter, 2 LDS dbufs (128 KiB).
//   ds_reads: P1/P2 (buf0), P5/P6 (buf1) only -> regions consumable after.
//   stages (1 half-tile = 2 gload_lds per phase):
//     P1:(t1,B0) P2:(t1,B1) P3:(t0+2,A0) P4:(t0+2,A1)
//     P5:(t0+2,B0) P6:(t0+2,B1) P7:(t1+2,A0) P8:(t1+2,A1)
//   vmcnt(4) at P4/P8 only (in-order retirement => stages 2+ phases old
//   landed); last iter: P4 uses vmcnt(0) (P3..P8 stages skipped).
// LDS row = 64 fp16 = 8 x 16B chunks; chunk swizzle c ^= (row & 7) on both
// stage-source and ds_read (rule #21) -> conflict-free b128 reads.
// ---------------------------------------------------------------------------
template<int NRELU, int OUT_HALF>
__global__ __launch_bounds__(512, 2)
void gemm_8phase(const _Float16* __restrict__ A,
                 const _Float16* __restrict__ Bt,
                 const float* __restrict__ bias,
                 void* __restrict__ Cout,
                 int M, int N, int K)
{
    __shared__ _Float16 lds[65536];   // 128 KiB: [buf][A 32KB | B 32KB]

    const int tid  = threadIdx.x;
    const int lane = tid & 63;
    const int wid  = tid >> 6;
    const int wr   = wid >> 2;        // 0..1
    const int wc   = wid & 3;         // 0..3

    // T1 bijective XCD swizzle (grids 256 / 768, both % 8 == 0)
    const int gx   = gridDim.x;
    const int nwg  = gx * gridDim.y;
    const int orig = blockIdx.y * gx + blockIdx.x;
    const int swz  = (orig & 7) * (nwg >> 3) + (orig >> 3);
    const int brow = (swz / gx) * 256;
    const int bcol = (swz % gx) * 256;

    f32x4 acc[8][4];
    #pragma unroll
    for (int mb = 0; mb < 8; ++mb)
        #pragma unroll
        for (int nb = 0; nb < 4; ++nb)
            acc[mb][nb] = (f32x4){0.f, 0.f, 0.f, 0.f};

    auto STAGE = [&](int t, int h){
        const _Float16* src = (h < 2) ? A : Bt;
        const int rb = ((h < 2) ? brow : bcol) + (h & 1)*128;
        char* dst = (char*)lds + (t & 1)*65536 + h*16384;
        #pragma unroll
        for (int j2 = 0; j2 < 2; ++j2){
            const int cl   = j2*512 + tid;
            const int srow = cl >> 3;
            const int gch  = (cl & 7) ^ (srow & 7);
            gload_lds16(src + (size_t)(rb + srow)*K + (size_t)t*64 + gch*8,
                        dst + cl*16);
        }
    };

    // per-lane fragment read offsets (bytes): row*128 + swizzled-chunk*16
    const int r15 = lane & 15;
    const int g   = lane >> 4;
    const int x7  = r15 & 7;
    const int aro = (wr*128 + r15) * 128;
    const int bro = 32768 + (wc*64 + r15) * 128;
    const int a0o = aro + ((g     ) ^ x7) * 16;   // ks=0
    const int a1o = aro + ((4 + g ) ^ x7) * 16;   // ks=1
    const int b0o = bro + ((g     ) ^ x7) * 16;
    const int b1o = bro + ((4 + g ) ^ x7) * 16;

    half8 af[8][2], bf[4][2];
    auto LDA = [&](int mb, const char* base){
        af[mb][0] = *reinterpret_cast<const half8*>(base + a0o + mb*2048);
        af[mb][1] = *reinterpret_cast<const half8*>(base + a1o + mb*2048);
    };
    auto LDB = [&](int nb, const char* base){
        bf[nb][0] = *reinterpret_cast<const half8*>(base + b0o + nb*2048);
        bf[nb][1] = *reinterpret_cast<const half8*>(base + b1o + nb*2048);
    };

#define MFMA_Q(MB0, NB0)                                                     \
    __builtin_amdgcn_s_setprio(1);                                           \
    _Pragma("unroll")                                                        \
    for (int m_ = 0; m_ < 4; ++m_){                                          \
        _Pragma("unroll")                                                    \
        for (int n_ = 0; n_ < 2; ++n_){                                      \
            acc[(MB0)+m_][(NB0)+n_] = __builtin_amdgcn_mfma_f32_16x16x32_f16(\
                af[(MB0)+m_][0], bf[(NB0)+n_][0], acc[(MB0)+m_][(NB0)+n_],0,0,0);\
            acc[(MB0)+m_][(NB0)+n_] = __builtin_amdgcn_mfma_f32_16x16x32_f16(\
                af[(MB0)+m_][1], bf[(NB0)+n_][1], acc[(MB0)+m_][(NB0)+n_],0,0,0);\
        }                                                                    \
    }                                                                        \
    __builtin_amdgcn_s_setprio(0);

    const char* b0p = (const char*)lds;
    const char* b1p = (const char*)lds + 65536;
    const int NI = K >> 7;   // 8 iters (2 K-tiles of 64 each per iter)

    // prologue: tile0 fully, tile1 halves A0,A1 (12 loads); vmcnt(4) leaves
    // tile1's 2 halves outstanding -> tile0 landed.
    STAGE(0,0); STAGE(0,1); STAGE(0,2); STAGE(0,3);
    STAGE(1,0); STAGE(1,1);
    asm volatile("s_waitcnt vmcnt(4)" ::: "memory");
    BAR();

    for (int j = 0; j < NI; ++j){
        const int t0 = 2*j, t1 = 2*j + 1;
        const bool last = (j == NI - 1);

        // ---- P1: reads af[0-3], bf[0-1] of buf0 ----
        #pragma unroll
        for (int mb = 0; mb < 4; ++mb) LDA(mb, b0p);
        #pragma unroll
        for (int nb = 0; nb < 2; ++nb) LDB(nb, b0p);
        STAGE(t1, 2);
        LGKM0(); BAR();
        MFMA_Q(0, 0);
        BAR();

        // ---- P2: reads af[4-7], bf[2-3] of buf0 ----
        #pragma unroll
        for (int mb = 4; mb < 8; ++mb) LDA(mb, b0p);
        #pragma unroll
        for (int nb = 2; nb < 4; ++nb) LDB(nb, b0p);
        STAGE(t1, 3);
        LGKM0(); BAR();
        MFMA_Q(4, 2);
        BAR();

        // ---- P3 ----
        if (!last) STAGE(t0 + 2, 0);
        BAR();
        MFMA_Q(0, 2);
        BAR();

        // ---- P4 ----
        if (!last) STAGE(t0 + 2, 1);
        BAR();
        MFMA_Q(4, 0);
        if (last) asm volatile("s_waitcnt vmcnt(0)" ::: "memory");
        else      asm volatile("s_waitcnt vmcnt(4)" ::: "memory");
        BAR();

        // ---- P5: reads af[0-3], bf[0-1] of buf1 ----
        #pragma unroll
        for (int mb = 0; mb < 4; ++mb) LDA(mb, b1p);
        #pragma unroll
        for (int nb = 0; nb < 2; ++nb) LDB(nb, b1p);
        if (!last) STAGE(t0 + 2, 2);
        LGKM0(); BAR();
        MFMA_Q(0, 0);
        BAR();

        // ---- P6 ----
        #pragma unroll
        for (int mb = 4; mb < 8; ++mb) LDA(mb, b1p);
        #pragma unroll
        for (int nb = 2; nb < 4; ++nb) LDB(nb, b1p);
        if (!last) STAGE(t0 + 2, 3);
        LGKM0(); BAR();
        MFMA_Q(4, 2);
        BAR();

        // ---- P7 ----
        if (!last) STAGE(t1 + 2, 0);
        BAR();
        MFMA_Q(0, 2);
        BAR();

        // ---- P8 ----
        if (!last) STAGE(t1 + 2, 1);
        BAR();
        MFMA_Q(4, 0);
        if (!last) asm volatile("s_waitcnt vmcnt(4)" ::: "memory");
        BAR();
    }

    // epilogue: C/D layout col=lane&15, row=(lane>>4)*4+reg  [m89/m91]
    const int lc  = lane & 15;
    const int lr4 = (lane >> 4) * 4;
    #pragma unroll
    for (int nb = 0; nb < 4; ++nb){
        const int col = bcol + wc*64 + nb*16 + lc;
        const float bv = bias[col];
        #pragma unroll
        for (int mb = 0; mb < 8; ++mb){
            const int rowg = brow + wr*128 + mb*16 + lr4;
            #pragma unroll
            for (int r = 0; r < 4; ++r){
                float v = acc[mb][nb][r] + bv;
                if (NRELU) v = fmaxf(v, 0.f);
                if (OUT_HALF)
                    ((_Float16*)Cout)[(size_t)(rowg + r)*N + col] = (_Float16)v;
                else
                    ((float*)Cout)[(size_t)(rowg + r)*N + col] = v;
            }
        }
    }
#undef MFMA_Q
}

// ---------------------------------------------------------------------------
// launcher
// ---------------------------------------------------------------------------
extern "C" void kernel_launch(void* const* d_in, const int* in_sizes, int n_in,
                              void* d_out, int out_size, void* d_ws, size_t ws_size,
                              hipStream_t stream)
{
    const float* e1     = (const float*)d_in[0];
    const float* e2     = (const float*)d_in[1];
    const float* interv = (const float*)d_in[2];
    const float* W1     = (const float*)d_in[3];
    const float* b1     = (const float*)d_in[4];
    const float* W2     = (const float*)d_in[5];
    const float* b2     = (const float*)d_in[6];
    const float* W3     = (const float*)d_in[7];
    const float* b3     = (const float*)d_in[8];
    const float* Wd1    = (const float*)d_in[9];
    const float* bd1    = (const float*)d_in[10];
    const float* Wd2    = (const float*)d_in[11];
    const float* bd2    = (const float*)d_in[12];
    const float* Wd3    = (const float*)d_in[13];
    const float* bd3    = (const float*)d_in[14];

    float* out = (float*)d_out;

    char* ws = (char*)d_ws;
    double*   acc   = (double*)ws;                                   // 256 B
    _Float16* hh2   = (_Float16*)(ws + 256);                         // 32 MB
    _Float16* Wd2t  = (_Float16*)(ws + 256 + (size_t)32*1024*1024);  // 2 MB
    _Float16* Wd3t  = (_Float16*)(ws + 256 + (size_t)34*1024*1024);  // 6 MB
    _Float16* hh1   = (_Float16*)d_out;  // scratch in d_out, dead before GEMM3

    hipLaunchKernelGGL(init_acc, dim3(1), dim3(64), 0, stream, acc);

    hipLaunchKernelGGL(flow_kernel, dim3(BB/256, ZD), dim3(256), 0, stream,
                       e1, e2, interv, W1, b1, W2, b2, W3, b3, acc);

    hipLaunchKernelGGL(convT_kernel, dim3(DH/32, DH/32), dim3(256), 0, stream,
                       Wd2, Wd2t, DH, DH);
    hipLaunchKernelGGL(convT_kernel, dim3(DX/32, DH/32), dim3(256), 0, stream,
                       Wd3, Wd3t, DH, DX);

    hipLaunchKernelGGL(dec1_tiled, dim3(M2/32), dim3(256), 0, stream,
                       e1, e2, Wd1, bd1, hh1);

    hipLaunchKernelGGL((gemm_8phase<1,1>), dim3(DH/256, M2/256), dim3(512), 0, stream,
                       hh1, Wd2t, bd2, (void*)hh2, M2, DH, DH);

    hipLaunchKernelGGL((gemm_8phase<0,0>), dim3(DX/256, M2/256), dim3(512), 0, stream,
                       hh2, Wd3t, bd3, (void*)out, M2, DX, DH);

    hipLaunchKernelGGL(finalize_kernel, dim3(1), dim3(64), 0, stream, acc, out);
}